// Round 7
// baseline (29.070 us; speedup 1.0000x reference)
//
#include <hip/hip_runtime.h>
#include <hip/hip_bf16.h>

#define LEAKY 0.2f
#define B_TOT 8192
#define N_TOT 2048
#define D_TOT 128
#define BM 16

typedef float f32x4 __attribute__((ext_vector_type(4)));
typedef short bf16x8 __attribute__((ext_vector_type(8)));
typedef unsigned short u16x8 __attribute__((ext_vector_type(8)));

static __device__ __forceinline__ unsigned short f2bf(float x) {
    return __builtin_bit_cast(unsigned short, __float2bfloat16(x));
}

// ---------------- fast path ----------------

// Prep: block b handles disease rows (= k values) [b*32, b*32+32).
// Writes DnTf in MFMA-B-fragment order: uint4 index (kt*8+ct)*64 + kg*16 + cl
// holds bf16 pairs for B[k=kt*32+kg*8+j][col=ct*16+cl], j=0..7.
__global__ __launch_bounds__(256) void prep_kernel(const float* __restrict__ disease,
                                                   const float* __restrict__ ak,
                                                   float* __restrict__ q,
                                                   uint4* __restrict__ DnTf) {
    __shared__ float tile[32][129];   // +1 pad
    __shared__ float a_s[D_TOT];
    const int tid = threadIdx.x;
    const int b = blockIdx.x;
    const int r0 = b * 32;

    if (tid < D_TOT) a_s[tid] = ak[D_TOT + tid];
    #pragma unroll
    for (int t = 0; t < 4; ++t) {
        int idx = tid + t * 256;          // 0..1023 float4 slots
        int row = idx >> 5;
        int cv = (idx & 31) * 4;
        float4 v = *(const float4*)(disease + (size_t)(r0 + row) * D_TOT + cv);
        tile[row][cv] = v.x; tile[row][cv + 1] = v.y;
        tile[row][cv + 2] = v.z; tile[row][cv + 3] = v.w;
    }
    __syncthreads();

    const int wave = tid >> 6, lane = tid & 63;
    #pragma unroll
    for (int rr = 0; rr < 8; ++rr) {
        int r = wave * 8 + rr;
        float s = tile[r][lane] * a_s[lane] + tile[r][lane + 64] * a_s[lane + 64];
        #pragma unroll
        for (int off = 32; off; off >>= 1) s += __shfl_xor(s, off);
        if (lane == 0) q[r0 + r] = s;
    }

    #pragma unroll
    for (int h = 0; h < 2; ++h) {
        const int c  = tid + h * 256;     // 0..511
        const int kg = c >> 7;            // 0..3
        const int col = c & 127;
        const int ct = col >> 4, cl = col & 15;
        unsigned u[4];
        #pragma unroll
        for (int jj = 0; jj < 4; ++jj) {
            unsigned lo = f2bf(tile[kg * 8 + 2 * jj][col]);
            unsigned hi = f2bf(tile[kg * 8 + 2 * jj + 1][col]);
            u[jj] = lo | (hi << 16);
        }
        DnTf[((size_t)b * 8 + ct) * 64 + kg * 16 + cl] = make_uint4(u[0], u[1], u[2], u[3]);
    }
}

// Main: 512 blocks x 1024 threads (2 blocks/CU = 8 waves/SIMD). BM=16 rows.
// 16 waves = cw(2 col-halves) x kq(8 K-eighths).
// W = max(E1*eq1, E2*eq2) built in-register in A-frag layout (exp-free, exact).
__global__ __launch_bounds__(1024, 8) void gat_mfma(const float* __restrict__ patient,
                                                    const float* __restrict__ ak,
                                                    const float* __restrict__ q,
                                                    const unsigned short* __restrict__ DnTb,
                                                    float* __restrict__ out) {
    __shared__ __align__(16) float eq1_s[N_TOT];
    __shared__ __align__(16) float eq2_s[N_TOT];
    __shared__ float red_s[7][2][1024];   // [kq-1][cw][t*256+(kg*4+i)*16+cl]
    __shared__ float a_s[D_TOT];
    __shared__ float p_s[BM], E1_s[BM], E2_s[BM], S_s[BM];
    __shared__ float red16[16];

    const int tid  = threadIdx.x;
    const int wave = tid >> 6;
    const int lane = tid & 63;
    const int b0   = blockIdx.x * BM;

    if (tid < D_TOT) a_s[tid] = ak[tid];
    __syncthreads();

    // eq1/eq2 + qmax partials (2 elements per thread)
    float mx = -1e30f;
    for (int i = tid; i < N_TOT; i += 1024) {
        float qq = q[i];
        eq1_s[i] = __expf(qq);
        eq2_s[i] = __expf(LEAKY * qq);
        mx = fmaxf(mx, qq);
    }
    #pragma unroll
    for (int off = 32; off; off >>= 1) mx = fmaxf(mx, __shfl_xor(mx, off));
    if (lane == 0) red16[wave] = mx;

    // p-dot: wave w handles row w
    {
        const float* pr = patient + (size_t)(b0 + wave) * D_TOT;
        float s = pr[lane] * a_s[lane] + pr[lane + 64] * a_s[lane + 64];
        #pragma unroll
        for (int off = 32; off; off >>= 1) s += __shfl_xor(s, off);
        if (lane == 0) p_s[wave] = s;
    }
    __syncthreads();

    if (tid < BM) {
        float qmax = red16[0];
        #pragma unroll
        for (int i = 1; i < 16; ++i) qmax = fmaxf(qmax, red16[i]);
        const float pv = p_s[tid];
        const float xm = pv + qmax;
        const float m = fmaxf(xm, LEAKY * xm);    // row max (leaky monotonic)
        E1_s[tid] = __expf(pv - m);
        E2_s[tid] = __expf(LEAKY * pv - m);
    }
    __syncthreads();

    // S per row (wave w -> row w): S = sum_n max(E1*eq1, E2*eq2)  (exact w)
    {
        const float E1 = E1_s[wave], E2 = E2_s[wave];
        float s = 0.f;
        for (int n = lane; n < N_TOT; n += 64)
            s += fmaxf(E1 * eq1_s[n], E2 * eq2_s[n]);
        #pragma unroll
        for (int off = 32; off; off >>= 1) s += __shfl_xor(s, off);
        if (lane == 0) S_s[wave] = s;
    }
    __syncthreads();

    // ---- barrier-free MFMA K-loop ----
    const int cl = lane & 15;
    const int kg = lane >> 4;
    const int cw = wave & 1;          // 64-col half
    const int kq = wave >> 1;         // K eighth (0..7)

    const float E1A = E1_s[cl], E2A = E2_s[cl];

    f32x4 acc[4] = {};

    #pragma unroll 2
    for (int kt = kq * 8; kt < kq * 8 + 8; ++kt) {
        const int gk = kt * 32 + kg * 8;
        const float4 e1a = *(const float4*)&eq1_s[gk];
        const float4 e1b = *(const float4*)&eq1_s[gk + 4];
        const float4 e2a = *(const float4*)&eq2_s[gk];
        const float4 e2b = *(const float4*)&eq2_s[gk + 4];
        bf16x8 bf[4];
        #pragma unroll
        for (int t = 0; t < 4; ++t)
            bf[t] = *(const bf16x8*)(DnTb + (((size_t)kt * 8 + cw * 4 + t) * 64 + lane) * 8);

        const float e1v[8] = {e1a.x, e1a.y, e1a.z, e1a.w, e1b.x, e1b.y, e1b.z, e1b.w};
        const float e2v[8] = {e2a.x, e2a.y, e2a.z, e2a.w, e2b.x, e2b.y, e2b.z, e2b.w};
        u16x8 aw;
        #pragma unroll
        for (int j = 0; j < 8; ++j)
            aw[j] = f2bf(fmaxf(E1A * e1v[j], E2A * e2v[j]));
        const bf16x8 a0 = __builtin_bit_cast(bf16x8, aw);

        acc[0] = __builtin_amdgcn_mfma_f32_16x16x32_bf16(a0, bf[0], acc[0], 0, 0, 0);
        acc[1] = __builtin_amdgcn_mfma_f32_16x16x32_bf16(a0, bf[1], acc[1], 0, 0, 0);
        acc[2] = __builtin_amdgcn_mfma_f32_16x16x32_bf16(a0, bf[2], acc[2], 0, 0, 0);
        acc[3] = __builtin_amdgcn_mfma_f32_16x16x32_bf16(a0, bf[3], acc[3], 0, 0, 0);
    }

    // ---- split-K reduction ----
    __syncthreads();
    if (kq > 0) {
        float* rb = &red_s[kq - 1][cw][0];
        #pragma unroll
        for (int t = 0; t < 4; ++t)
            #pragma unroll
            for (int i = 0; i < 4; ++i)
                rb[t * 256 + (kg * 4 + i) * 16 + cl] = acc[t][i];
    }
    __syncthreads();
    if (kq == 0) {
        #pragma unroll
        for (int t = 0; t < 4; ++t)
            #pragma unroll
            for (int i = 0; i < 4; ++i) {
                const int idx = t * 256 + (kg * 4 + i) * 16 + cl;
                float s = acc[t][i];
                #pragma unroll
                for (int j = 0; j < 7; ++j) s += red_s[j][cw][idx];
                acc[t][i] = s;
            }
        float inv[4];
        #pragma unroll
        for (int i = 0; i < 4; ++i) inv[i] = 1.0f / S_s[kg * 4 + i];
        #pragma unroll
        for (int t = 0; t < 4; ++t)
            #pragma unroll
            for (int i = 0; i < 4; ++i) {
                const int row = b0 + kg * 4 + i;
                const int col = cw * 64 + t * 16 + cl;
                out[(size_t)row * D_TOT + col] =
                    patient[(size_t)row * D_TOT + col] + acc[t][i] * inv[i];
            }
    }
}

// ---------------- fallback path (round-1, known-passing) ----------------

__global__ __launch_bounds__(256) void pq_fb(const float* __restrict__ patient,
                                             const float* __restrict__ disease,
                                             const float* __restrict__ ak,
                                             float* __restrict__ p,
                                             float* __restrict__ q) {
    int gid  = blockIdx.x * blockDim.x + threadIdx.x;
    int wid  = gid >> 6;
    int lane = gid & 63;
    const float* src;
    const float* a;
    float* dst;
    if (wid < B_TOT) {
        src = patient + (size_t)wid * D_TOT; a = ak; dst = p + wid;
    } else {
        src = disease + (size_t)(wid - B_TOT) * D_TOT; a = ak + D_TOT; dst = q + (wid - B_TOT);
    }
    float s = src[lane] * a[lane] + src[lane + 64] * a[lane + 64];
    #pragma unroll
    for (int off = 32; off; off >>= 1) s += __shfl_xor(s, off);
    if (lane == 0) *dst = s;
}

#define FBP 16
#define FNT 256
__global__ __launch_bounds__(256) void gat_fb(const float* __restrict__ patient,
                                              const float* __restrict__ disease,
                                              const float* __restrict__ p,
                                              const float* __restrict__ q,
                                              float* __restrict__ out) {
    __shared__ float q_s[N_TOT];
    __shared__ float w_s[FBP][FNT];
    __shared__ float m_s[FBP], S_s[FBP], pp_s[FBP];
    const int tid = threadIdx.x;
    const int b0  = blockIdx.x * FBP;
    for (int i = tid; i < N_TOT; i += 256) q_s[i] = q[i];
    if (tid < FBP) pp_s[tid] = p[b0 + tid];
    __syncthreads();
    const int wave = tid >> 6, lane = tid & 63;
    for (int pi = wave * 4; pi < wave * 4 + 4; ++pi) {
        float pp = pp_s[pi];
        float mx = -1e30f;
        for (int n = lane; n < N_TOT; n += 64) {
            float x = pp + q_s[n]; x = x > 0.0f ? x : LEAKY * x; mx = fmaxf(mx, x);
        }
        #pragma unroll
        for (int off = 32; off; off >>= 1) mx = fmaxf(mx, __shfl_xor(mx, off));
        float sum = 0.0f;
        for (int n = lane; n < N_TOT; n += 64) {
            float x = pp + q_s[n]; x = x > 0.0f ? x : LEAKY * x; sum += __expf(x - mx);
        }
        #pragma unroll
        for (int off = 32; off; off >>= 1) sum += __shfl_xor(sum, off);
        if (lane == 0) { m_s[pi] = mx; S_s[pi] = sum; }
    }
    __syncthreads();
    const int d2 = tid & 31;
    const int pg = tid >> 5;
    const int p0 = 2 * pg, p1 = 2 * pg + 1;
    float4 acc0 = make_float4(0.f, 0.f, 0.f, 0.f);
    float4 acc1 = make_float4(0.f, 0.f, 0.f, 0.f);
    for (int n0 = 0; n0 < N_TOT; n0 += FNT) {
        __syncthreads();
        for (int i = tid; i < FBP * FNT; i += 256) {
            int pi = i >> 8;
            int nt = i & (FNT - 1);
            float x = pp_s[pi] + q_s[n0 + nt];
            x = x > 0.0f ? x : LEAKY * x;
            w_s[pi][nt] = __expf(x - m_s[pi]);
        }
        __syncthreads();
        const float* drow = disease + (size_t)n0 * D_TOT + d2 * 4;
        #pragma unroll 4
        for (int nt = 0; nt < FNT; ++nt) {
            float4 dv = *reinterpret_cast<const float4*>(drow + (size_t)nt * D_TOT);
            float w0 = w_s[p0][nt];
            float w1 = w_s[p1][nt];
            acc0.x += w0 * dv.x; acc0.y += w0 * dv.y; acc0.z += w0 * dv.z; acc0.w += w0 * dv.w;
            acc1.x += w1 * dv.x; acc1.y += w1 * dv.y; acc1.z += w1 * dv.z; acc1.w += w1 * dv.w;
        }
    }
    const float inv0 = 1.0f / S_s[p0];
    const float inv1 = 1.0f / S_s[p1];
    {
        size_t off = (size_t)(b0 + p0) * D_TOT + d2 * 4;
        float4 pf = *reinterpret_cast<const float4*>(patient + off);
        float4 o;
        o.x = pf.x + acc0.x * inv0; o.y = pf.y + acc0.y * inv0;
        o.z = pf.z + acc0.z * inv0; o.w = pf.w + acc0.w * inv0;
        *reinterpret_cast<float4*>(reinterpret_cast<float*>(out) + off) = o;
    }
    {
        size_t off = (size_t)(b0 + p1) * D_TOT + d2 * 4;
        float4 pf = *reinterpret_cast<const float4*>(patient + off);
        float4 o;
        o.x = pf.x + acc1.x * inv1; o.y = pf.y + acc1.y * inv1;
        o.z = pf.z + acc1.z * inv1; o.w = pf.w + acc1.w * inv1;
        *reinterpret_cast<float4*>(reinterpret_cast<float*>(out) + off) = o;
    }
}

extern "C" void kernel_launch(void* const* d_in, const int* in_sizes, int n_in,
                              void* d_out, int out_size, void* d_ws, size_t ws_size,
                              hipStream_t stream) {
    const float* patient = (const float*)d_in[0];   // 8192 x 128
    const float* disease = (const float*)d_in[1];   // 2048 x 128
    const float* ak      = (const float*)d_in[2];   // 256
    float* out = (float*)d_out;

    const size_t need_fast = (size_t)512 * 1024 + 8192;   // DnTf (512KB) + q (8KB)
    if (ws_size >= need_fast) {
        uint4* DnTf = (uint4*)d_ws;                          // 64x8x64 uint4 = 512KB
        float* q    = (float*)((char*)d_ws + 512 * 1024);    // 2048 f32
        prep_kernel<<<N_TOT / 32, 256, 0, stream>>>(disease, ak, q, DnTf);
        gat_mfma<<<B_TOT / BM, 1024, 0, stream>>>(patient, ak, q,
                                                  (const unsigned short*)DnTf, out);
    } else {
        float* p = (float*)d_ws;          // 8192 f32
        float* q = p + B_TOT;             // 2048 f32
        pq_fb<<<(B_TOT + N_TOT) / 4, 256, 0, stream>>>(patient, disease, ak, p, q);
        gat_fb<<<B_TOT / FBP, 256, 0, stream>>>(patient, disease, p, q, out);
    }
}